// Round 3
// baseline (363.577 us; speedup 1.0000x reference)
//
#include <hip/hip_runtime.h>
#include <math.h>

#define PP 7
#define CCH 256

// Fractional per-pixel coverage at column `colf` of interval [a, b] (clipped box),
// reproducing _coverage's edge weighting. colf is an integer-valued float.
__device__ __forceinline__ float coverage(float colf, float a, float b) {
    float af = floorf(a);
    float bc = ceilf(b);
    float v  = (colf >= af && colf < bc) ? 1.0f : 0.0f;
    float wl = (colf == af) ? (1.0f + af - a) : 1.0f;
    float wr = (colf == bc - 1.0f) ? (1.0f + b - bc) : 1.0f;
    return v * wl * wr;
}

struct AxisTab {
    int   lo[14], hi[14];
    float wl[14], wh[14];
    float cu_lo[14], cu_hi[14], co_lo[14], co_hi[14];
};

__global__ __launch_bounds__(256) void roi_pair_kernel(
    const float* __restrict__ f0, const float* __restrict__ f1,
    const float* __restrict__ f2, const float* __restrict__ f3,
    const float* __restrict__ bh, const float* __restrict__ bo,
    float* __restrict__ out, int K)
{
    const int k  = blockIdx.x;   // box pair
    const int py = blockIdx.y;   // output bin row 0..6
    const int c  = threadIdx.x;  // channel

    __shared__ AxisTab sx;                     // x-axis tables, 14 samples
    __shared__ int   s_ylo[2], s_yhi[2];       // this bin-row's two y samples
    __shared__ float s_wyl[2], s_wyh[2];
    __shared__ float s_cyu_lo[2], s_cyu_hi[2], s_cyo_lo[2], s_cyo_hi[2];

    // ---- per-box scalar metadata (uniform across threads; cheap) ----
    const float hx1 = bh[k*5+1], hy1 = bh[k*5+2], hx2 = bh[k*5+3], hy2 = bh[k*5+4];
    const float px1 = bo[k*5+1], py1 = bo[k*5+2], px2 = bo[k*5+3], py2 = bo[k*5+4];
    const int   bimg = (int)bh[k*5+0];

    const float ux1 = fminf(hx1, px1), uy1 = fminf(hy1, py1);
    const float ux2 = fmaxf(hx2, px2), uy2 = fmaxf(hy2, py2);

    const float su = sqrtf((ux2-ux1)*(uy2-uy1));
    const float so = sqrtf((px2-px1)*(py2-py1));
    const float s  = fminf(su, so);
    float lvf = floorf(4.0f + log2f(s/224.0f + 1e-6f));
    lvf = fminf(fmaxf(lvf, 2.0f), 5.0f);
    const int lv = (int)lvf - 2;

    const float scales[4] = {0.25f, 0.125f, 0.0625f, 0.03125f};
    const int   dims[4]   = {128, 64, 32, 16};
    const float scale = scales[lv];
    const int   W = dims[lv], H = W;
    const float Wf = (float)W, Hf = (float)H;
    const float* feat = (lv == 0) ? f0 : (lv == 1) ? f1 : (lv == 2) ? f2 : f3;

    // scaled union / object boxes
    const float usx1 = ux1*scale, usy1 = uy1*scale, usx2 = ux2*scale, usy2 = uy2*scale;
    const float osx1 = px1*scale, osy1 = py1*scale, osx2 = px2*scale, osy2 = py2*scale;
    // clipped versions (coverage uses clipped; sampling grid uses unclipped)
    const float cux1 = fminf(fmaxf(usx1, 0.f), Wf), cux2 = fminf(fmaxf(usx2, 0.f), Wf);
    const float cuy1 = fminf(fmaxf(usy1, 0.f), Hf), cuy2 = fminf(fmaxf(usy2, 0.f), Hf);
    const float cox1 = fminf(fmaxf(osx1, 0.f), Wf), cox2 = fminf(fmaxf(osx2, 0.f), Wf);
    const float coy1 = fminf(fmaxf(osy1, 0.f), Hf), coy2 = fminf(fmaxf(osy2, 0.f), Hf);
    const float roi_w = fmaxf(usx2 - usx1, 1.0f);
    const float roi_h = fmaxf(usy2 - usy1, 1.0f);

    // ---- axis tables into LDS (x on wave 0 lanes 0..13, y on wave 1 lanes 0..1) ----
    if (threadIdx.x < 14) {
        const int i = threadIdx.x;
        const float t = (float)(i >> 1) + 0.25f + 0.5f*(float)(i & 1);
        const float p = usx1 + t * (roi_w / 7.0f);
        const float valid = (p >= -1.0f && p <= Wf) ? 1.0f : 0.0f;
        float cc  = fmaxf(p, 0.0f);
        const float lo0 = floorf(cc);
        const bool top = (lo0 >= Wf - 1.0f);
        const float lo = top ? (Wf - 1.0f) : lo0;
        const float hi = top ? (Wf - 1.0f) : (lo0 + 1.0f);
        cc = top ? (Wf - 1.0f) : cc;
        const float frac = cc - lo;
        sx.lo[i] = (int)lo;  sx.hi[i] = (int)hi;
        sx.wl[i] = (1.0f - frac) * valid;  sx.wh[i] = frac * valid;
        sx.cu_lo[i] = coverage(lo, cux1, cux2);
        sx.cu_hi[i] = coverage(hi, cux1, cux2);
        sx.co_lo[i] = coverage(lo, cox1, cox2);
        sx.co_hi[i] = coverage(hi, cox1, cox2);
    } else if (threadIdx.x >= 64 && threadIdx.x < 66) {
        const int isy = threadIdx.x - 64;
        const int i = 2*py + isy;
        const float t = (float)(i >> 1) + 0.25f + 0.5f*(float)(i & 1);
        const float p = usy1 + t * (roi_h / 7.0f);
        const float valid = (p >= -1.0f && p <= Hf) ? 1.0f : 0.0f;
        float cc  = fmaxf(p, 0.0f);
        const float lo0 = floorf(cc);
        const bool top = (lo0 >= Hf - 1.0f);
        const float lo = top ? (Hf - 1.0f) : lo0;
        const float hi = top ? (Hf - 1.0f) : (lo0 + 1.0f);
        cc = top ? (Hf - 1.0f) : cc;
        const float frac = cc - lo;
        s_ylo[isy] = (int)lo;  s_yhi[isy] = (int)hi;
        s_wyl[isy] = (1.0f - frac) * valid;  s_wyh[isy] = frac * valid;
        s_cyu_lo[isy] = coverage(lo, cuy1, cuy2);
        s_cyu_hi[isy] = coverage(hi, cuy1, cuy2);
        s_cyo_lo[isy] = coverage(lo, coy1, coy2);
        s_cyo_hi[isy] = coverage(hi, coy1, coy2);
    }
    __syncthreads();

    // ---- gather + accumulate ----
    const float* fc = feat + (size_t)(bimg * CCH + c) * (H * W);

    float accs[7] = {0,0,0,0,0,0,0};  // statically indexed via full unroll below

    #pragma unroll
    for (int isy = 0; isy < 2; ++isy) {
        const int   ylo = s_ylo[isy], yhi = s_yhi[isy];
        const float wyl = s_wyl[isy], wyh = s_wyh[isy];
        const float cyu0 = s_cyu_lo[isy], cyu1 = s_cyu_hi[isy];
        const float cyo0 = s_cyo_lo[isy], cyo1 = s_cyo_hi[isy];
        const float* rlo = fc + ylo * W;
        const float* rhi = fc + yhi * W;
        #pragma unroll
        for (int ix = 0; ix < 14; ++ix) {
            const int pxb = ix >> 1;                 // compile-time under unroll
            const int xlo = sx.lo[ix], xhi = sx.hi[ix];
            const float wxl = sx.wl[ix], wxh = sx.wh[ix];
            const float cxu0 = sx.cu_lo[ix], cxu1 = sx.cu_hi[ix];
            const float cxo0 = sx.co_lo[ix], cxo1 = sx.co_hi[ix];
            const float w00 = wyl*wxl*fmaxf(cyu0*cxu0, cyo0*cxo0);
            const float w01 = wyl*wxh*fmaxf(cyu0*cxu1, cyo0*cxo1);
            const float w10 = wyh*wxl*fmaxf(cyu1*cxu0, cyo1*cxo0);
            const float w11 = wyh*wxh*fmaxf(cyu1*cxu1, cyo1*cxo1);
            const float a00 = rlo[xlo], a01 = rlo[xhi];
            const float a10 = rhi[xlo], a11 = rhi[xhi];
            accs[pxb] += w00*a00 + w01*a01 + w10*a10 + w11*a11;
        }
    }

    // ---- store: out[k][c][py][0..6], 7 contiguous floats per thread ----
    float* op = out + ((size_t)k * CCH + c) * (PP * PP) + py * PP;
    #pragma unroll
    for (int pxb = 0; pxb < 7; ++pxb) op[pxb] = accs[pxb] * 0.25f;
}

extern "C" void kernel_launch(void* const* d_in, const int* in_sizes, int n_in,
                              void* d_out, int out_size, void* d_ws, size_t ws_size,
                              hipStream_t stream) {
    const float* f0 = (const float*)d_in[0];
    const float* f1 = (const float*)d_in[1];
    const float* f2 = (const float*)d_in[2];
    const float* f3 = (const float*)d_in[3];
    const float* bh = (const float*)d_in[4];
    const float* bo = (const float*)d_in[5];
    float* out = (float*)d_out;
    const int K = in_sizes[4] / 5;

    dim3 grid(K, PP);
    roi_pair_kernel<<<grid, CCH, 0, stream>>>(f0, f1, f2, f3, bh, bo, out, K);
}